// Round 3
// baseline (393.951 us; speedup 1.0000x reference)
//
#include <hip/hip_runtime.h>
#include <stdint.h>

// R7: revert angle to 2-pair granularity (R6's 4-pair burst REGRESSED
// 198->217us: L1-miss-queue backpressure; model = L1 miss-processing
// throughput ~3cyc/miss/CU, 2 misses/pair -> 6.1 cyc/pair measured) and
// add a persistent grid-stride loop with next-iteration index prefetch:
// hides the per-thread idx-load->gather serial chain head that one-shot
// threads pay in full, while keeping gather bursts at 4/iteration.
// Keep fast_acos (absmax identical 0.03125) + vectorized encode.
// Evidence R4 vs R6 A/B: MLP-per-thread hurts, VALU is idle (14-18%),
// FETCH/WRITE constant -> throughput-bound gather, not BW, not VALU.
// The ~160us gap between bench total and angle dispatches is harness
// restore overhead (same gap for scalar R0 encode and vector R6 encode).

typedef int            v2i  __attribute__((ext_vector_type(2)));
typedef float          v2f  __attribute__((ext_vector_type(2)));
typedef float          v4f  __attribute__((ext_vector_type(4)));
typedef unsigned short v4s  __attribute__((ext_vector_type(4)));

__device__ __forceinline__ uint16_t oct8_encode(float x, float y, float z) {
    float s   = fabsf(x) + fabsf(y) + fabsf(z);
    float inv = 1.0f / s;                        // min ||vec|| ~1e-2 for this data
    float u = x * inv, v = y * inv;
    if (z < 0.0f) {                              // fold lower hemisphere
        float uo = (1.0f - fabsf(v)) * (u >= 0.0f ? 1.0f : -1.0f);
        float vo = (1.0f - fabsf(u)) * (v >= 0.0f ? 1.0f : -1.0f);
        u = uo; v = vo;
    }
    int iu = (int)lrintf(fminf(fmaxf(u, -1.0f), 1.0f) * 127.0f);
    int iv = (int)lrintf(fminf(fmaxf(v, -1.0f), 1.0f) * 127.0f);
    return (uint16_t)((iu & 0xff) | ((iv & 0xff) << 8));
}

__device__ __forceinline__ float3 oct8_decode(uint32_t p) {
    float u = (float)(int8_t)(p & 0xffu) * (1.0f / 127.0f);
    float v = (float)(int8_t)((p >> 8) & 0xffu) * (1.0f / 127.0f);
    float z = 1.0f - fabsf(u) - fabsf(v);
    float t = fmaxf(-z, 0.0f);                   // >0 only in lower hemisphere
    float x = u + (u >= 0.0f ? -t : t);
    float y = v + (v >= 0.0f ? -t : t);
    return make_float3(x, y, z);                 // unnormalized; fixed by rsqrt later
}

// acos via A&S 4.4.47: acos(x) = sqrt(1-x) * P(x) on [0,1], reflected for
// x<0. |poly err| <= 2e-8; sqrt via t*rsq(t) (t >= 0.05 since |x|<=0.95).
__device__ __forceinline__ float fast_acos(float x) {
    float a = fabsf(x);
    float r = fmaf(-0.0012624911f, a, 0.0066700901f);
    r = fmaf(r, a, -0.0170881256f);
    r = fmaf(r, a,  0.0308918810f);
    r = fmaf(r, a, -0.0501743046f);
    r = fmaf(r, a,  0.0889789874f);
    r = fmaf(r, a, -0.2145988016f);
    r = fmaf(r, a,  1.5707963050f);
    float t = 1.0f - a;                          // in [0.05, 1]
    r *= t * __frsqrt_rn(t);                     // sqrt(1-a), 2 instrs
    return x >= 0.0f ? r : 3.14159274f - r;
}

__device__ __forceinline__ float angle_pair(uint32_t pa, uint32_t pb) {
    float3 a = oct8_decode(pa);
    float3 b = oct8_decode(pb);
    float num = fmaf(a.x, b.x, fmaf(a.y, b.y, a.z * b.z));
    float la  = fmaf(a.x, a.x, fmaf(a.y, a.y, a.z * a.z));
    float lb  = fmaf(b.x, b.x, fmaf(b.y, b.y, b.z * b.z));
    float c   = num * __frsqrt_rn(la * lb);
    c = fminf(fmaxf(c, -1.0f), 1.0f);
    return fast_acos(0.95f * c);
}

// 4 edges/thread: 3x float4 NT loads (48B, fully coalesced) + ushort4 store.
__global__ void __launch_bounds__(256)
encode_kernel(const float* __restrict__ vec,
              uint16_t* __restrict__ tab, int E) {
    int e0 = (blockIdx.x * blockDim.x + threadIdx.x) * 4;
    if (e0 + 3 < E) {
        v4f a = __builtin_nontemporal_load((const v4f*)&vec[(size_t)e0 * 3 + 0]);
        v4f b = __builtin_nontemporal_load((const v4f*)&vec[(size_t)e0 * 3 + 4]);
        v4f c = __builtin_nontemporal_load((const v4f*)&vec[(size_t)e0 * 3 + 8]);
        v4s t;
        t.x = oct8_encode(a.x, a.y, a.z);
        t.y = oct8_encode(a.w, b.x, b.y);
        t.z = oct8_encode(b.z, b.w, c.x);
        t.w = oct8_encode(c.y, c.z, c.w);
        *(v4s*)&tab[e0] = t;                     // normal store: angle reads it from L2
    } else if (e0 < E) {
        for (int e = e0; e < E; ++e)
            tab[e] = oct8_encode(vec[3 * e + 0], vec[3 * e + 1], vec[3 * e + 2]);
    }
}

// Persistent grid-stride loop, 2 pairs per iteration.
// Steady state per iteration: 4 gathers (current) + 2 idx loads (next) in
// flight; next-iter index latency hidden under current iter's gathers and
// compute. Gather burst stays at 4 (R6 showed 8-bursts regress).
__global__ void __launch_bounds__(256)
angle_kernel(const uint16_t* __restrict__ tab,
             const int* __restrict__ src,
             const int* __restrict__ dst,
             float* __restrict__ out, int A) {
    const int nthreads = gridDim.x * blockDim.x;
    const int tid = blockIdx.x * blockDim.x + threadIdx.x;
    const int nchunk = A >> 1;                   // full 2-pair chunks

    int c = tid;
    v2i s2, d2;
    if (c < nchunk) {
        s2 = __builtin_nontemporal_load((const v2i*)&src[2 * c]);
        d2 = __builtin_nontemporal_load((const v2i*)&dst[2 * c]);
    }
    while (c < nchunk) {
        // issue current chunk's 4 gathers first
        uint32_t ps0 = tab[s2.x], ps1 = tab[s2.y];
        uint32_t pd0 = tab[d2.x], pd1 = tab[d2.y];
        // prefetch next chunk's indices while gathers are in flight
        int cn = c + nthreads;
        v2i s2n, d2n;
        if (cn < nchunk) {
            s2n = __builtin_nontemporal_load((const v2i*)&src[2 * cn]);
            d2n = __builtin_nontemporal_load((const v2i*)&dst[2 * cn]);
        }
        v2f r;
        r.x = angle_pair(ps0, pd0);
        r.y = angle_pair(ps1, pd1);
        __builtin_nontemporal_store(r, (v2f*)&out[2 * c]);
        c = cn;
        s2 = s2n;
        d2 = d2n;
    }
    // odd tail (A odd): one pair, single thread
    if (tid == 0 && (A & 1)) {
        int k = A - 1;
        out[k] = angle_pair(tab[src[k]], tab[dst[k]]);
    }
}

// Fallback (workspace too small): gather raw vec + dist per endpoint.
__global__ void __launch_bounds__(256)
angle_fallback_kernel(const float* __restrict__ vec,
                      const float* __restrict__ dist,
                      const int* __restrict__ src,
                      const int* __restrict__ dst,
                      float* __restrict__ out, int A) {
    int i = blockIdx.x * blockDim.x + threadIdx.x;
    if (i >= A) return;
    int s = src[i];
    int d = dst[i];
    float sx = vec[3 * s + 0], sy = vec[3 * s + 1], sz = vec[3 * s + 2];
    float dx = vec[3 * d + 0], dy = vec[3 * d + 1], dz = vec[3 * d + 2];
    float ns = fmaxf(dist[s], 1e-5f);
    float nd = fmaxf(dist[d], 1e-5f);
    float c  = (sx * dx + sy * dy + sz * dz) / (ns * nd);
    out[i] = acosf(0.95f * c);
}

extern "C" void kernel_launch(void* const* d_in, const int* in_sizes, int n_in,
                              void* d_out, int out_size, void* d_ws, size_t ws_size,
                              hipStream_t stream) {
    const float* dist = (const float*)d_in[0];   // [E]
    const float* vec  = (const float*)d_in[1];   // [E,3]
    const int*   src  = (const int*)d_in[2];     // [A]
    const int*   dst  = (const int*)d_in[3];     // [A]
    float*       out  = (float*)d_out;           // [A]

    const int E = in_sizes[0];
    const int A = in_sizes[2];

    const int block = 256;
    if (ws_size >= (size_t)E * sizeof(uint16_t)) {
        uint16_t* tab = (uint16_t*)d_ws;
        int ethreads = (E + 3) / 4;
        encode_kernel<<<(ethreads + block - 1) / block, block, 0, stream>>>(vec, tab, E);
        // persistent grid: 8 blocks/CU x 256 CUs = 2048 blocks (32 waves/CU)
        int ablocks = 2048;
        int nchunk = A / 2;
        int maxblocks = (nchunk + block - 1) / block;
        if (ablocks > maxblocks) ablocks = maxblocks;
        angle_kernel<<<ablocks, block, 0, stream>>>(tab, src, dst, out, A);
    } else {
        angle_fallback_kernel<<<(A + block - 1) / block, block, 0, stream>>>(
            vec, dist, src, dst, out, A);
    }
}

// Round 4
// 355.822 us; speedup vs baseline: 1.1072x; 1.1072x over previous
//
#include <hip/hip_runtime.h>
#include <stdint.h>

// R8 = R4 structure (best measured: one-shot, 2 pairs/thread, 198us) with
// the table gathers converted to AGENT-SCOPE loads (L1-bypass).
// Evidence chain:
//   - R4 198us / R6 4-pair 217us / R7 persistent+prefetch 230us:
//     more MLP and SW pipelining both REGRESS -> not latency-bound.
//   - R2 (8MB table, spills L2) == R4 (4MB, L2-resident) at ~198us ->
//     not L2-residency/latency-bound either.
//   - VALUBusy 14-18%, HBM 12%, FETCH/WRITE constant across all shapes.
//   Model: per-CU L1/TCP port is the wall. Every gather lane is an L1 miss
//   (random 2B in 4MB); ~3 L1-port cyc/miss (lookup+fill+forward) x 2
//   misses/pair = 6.1 cyc/pair = measured. Fix: agent-scope relaxed loads
//   bypass the non-coherent L1 -> gather goes straight to L2 (per-XCD L2
//   has ~16 ch ~= 0.5 req/cyc/CU of headroom vs our 0.33 need).
// Keep: fast_acos (absmax bit-identical 0.03125 in R6/R7), vector encode.

typedef int            v2i  __attribute__((ext_vector_type(2)));
typedef float          v2f  __attribute__((ext_vector_type(2)));
typedef float          v4f  __attribute__((ext_vector_type(4)));
typedef unsigned short v4s  __attribute__((ext_vector_type(4)));

__device__ __forceinline__ uint16_t oct8_encode(float x, float y, float z) {
    float s   = fabsf(x) + fabsf(y) + fabsf(z);
    float inv = 1.0f / s;                        // min ||vec|| ~1e-2 for this data
    float u = x * inv, v = y * inv;
    if (z < 0.0f) {                              // fold lower hemisphere
        float uo = (1.0f - fabsf(v)) * (u >= 0.0f ? 1.0f : -1.0f);
        float vo = (1.0f - fabsf(u)) * (v >= 0.0f ? 1.0f : -1.0f);
        u = uo; v = vo;
    }
    int iu = (int)lrintf(fminf(fmaxf(u, -1.0f), 1.0f) * 127.0f);
    int iv = (int)lrintf(fminf(fmaxf(v, -1.0f), 1.0f) * 127.0f);
    return (uint16_t)((iu & 0xff) | ((iv & 0xff) << 8));
}

__device__ __forceinline__ float3 oct8_decode(uint32_t p) {
    float u = (float)(int8_t)(p & 0xffu) * (1.0f / 127.0f);
    float v = (float)(int8_t)((p >> 8) & 0xffu) * (1.0f / 127.0f);
    float z = 1.0f - fabsf(u) - fabsf(v);
    float t = fmaxf(-z, 0.0f);                   // >0 only in lower hemisphere
    float x = u + (u >= 0.0f ? -t : t);
    float y = v + (v >= 0.0f ? -t : t);
    return make_float3(x, y, z);                 // unnormalized; fixed by rsqrt later
}

// acos via A&S 4.4.47: acos(x) = sqrt(1-x) * P(x) on [0,1], reflected for
// x<0. |poly err| <= 2e-8; sqrt via t*rsq(t) (t >= 0.05 since |x|<=0.95).
__device__ __forceinline__ float fast_acos(float x) {
    float a = fabsf(x);
    float r = fmaf(-0.0012624911f, a, 0.0066700901f);
    r = fmaf(r, a, -0.0170881256f);
    r = fmaf(r, a,  0.0308918810f);
    r = fmaf(r, a, -0.0501743046f);
    r = fmaf(r, a,  0.0889789874f);
    r = fmaf(r, a, -0.2145988016f);
    r = fmaf(r, a,  1.5707963050f);
    float t = 1.0f - a;                          // in [0.05, 1]
    r *= t * __frsqrt_rn(t);                     // sqrt(1-a), 2 instrs
    return x >= 0.0f ? r : 3.14159274f - r;
}

// Agent-scope relaxed load: bypasses the non-coherent per-CU L1 (goes to
// L2 directly). Compiler still schedules vmcnt -> MLP across calls kept.
__device__ __forceinline__ uint32_t tab_gather(const uint16_t* __restrict__ tab,
                                               int idx) {
    return (uint32_t)__hip_atomic_load(&tab[idx], __ATOMIC_RELAXED,
                                       __HIP_MEMORY_SCOPE_AGENT);
}

__device__ __forceinline__ float angle_pair(uint32_t pa, uint32_t pb) {
    float3 a = oct8_decode(pa);
    float3 b = oct8_decode(pb);
    float num = fmaf(a.x, b.x, fmaf(a.y, b.y, a.z * b.z));
    float la  = fmaf(a.x, a.x, fmaf(a.y, a.y, a.z * a.z));
    float lb  = fmaf(b.x, b.x, fmaf(b.y, b.y, b.z * b.z));
    float c   = num * __frsqrt_rn(la * lb);
    c = fminf(fmaxf(c, -1.0f), 1.0f);
    return fast_acos(0.95f * c);
}

// 4 edges/thread: 3x float4 NT loads (48B, fully coalesced) + ushort4 store.
__global__ void __launch_bounds__(256)
encode_kernel(const float* __restrict__ vec,
              uint16_t* __restrict__ tab, int E) {
    int e0 = (blockIdx.x * blockDim.x + threadIdx.x) * 4;
    if (e0 + 3 < E) {
        v4f a = __builtin_nontemporal_load((const v4f*)&vec[(size_t)e0 * 3 + 0]);
        v4f b = __builtin_nontemporal_load((const v4f*)&vec[(size_t)e0 * 3 + 4]);
        v4f c = __builtin_nontemporal_load((const v4f*)&vec[(size_t)e0 * 3 + 8]);
        v4s t;
        t.x = oct8_encode(a.x, a.y, a.z);
        t.y = oct8_encode(a.w, b.x, b.y);
        t.z = oct8_encode(b.z, b.w, c.x);
        t.w = oct8_encode(c.y, c.z, c.w);
        *(v4s*)&tab[e0] = t;                     // normal store: angle reads it from L2
    } else if (e0 < E) {
        for (int e = e0; e < E; ++e)
            tab[e] = oct8_encode(vec[3 * e + 0], vec[3 * e + 1], vec[3 * e + 2]);
    }
}

// R4 shape: one-shot, 2 pairs/thread, 8B idx loads, 4 gathers in flight.
__global__ void __launch_bounds__(256)
angle_kernel(const uint16_t* __restrict__ tab,
             const int* __restrict__ src,
             const int* __restrict__ dst,
             float* __restrict__ out, int A) {
    int i = (blockIdx.x * blockDim.x + threadIdx.x) * 2;
    if (i + 1 < A) {
        v2i s2 = __builtin_nontemporal_load((const v2i*)&src[i]);
        v2i d2 = __builtin_nontemporal_load((const v2i*)&dst[i]);
        uint32_t ps0 = tab_gather(tab, s2.x);
        uint32_t ps1 = tab_gather(tab, s2.y);
        uint32_t pd0 = tab_gather(tab, d2.x);
        uint32_t pd1 = tab_gather(tab, d2.y);
        v2f r;
        r.x = angle_pair(ps0, pd0);
        r.y = angle_pair(ps1, pd1);
        __builtin_nontemporal_store(r, (v2f*)&out[i]);
    } else if (i < A) {
        int s = src[i], d = dst[i];
        out[i] = angle_pair(tab_gather(tab, s), tab_gather(tab, d));
    }
}

// Fallback (workspace too small): gather raw vec + dist per endpoint.
__global__ void __launch_bounds__(256)
angle_fallback_kernel(const float* __restrict__ vec,
                      const float* __restrict__ dist,
                      const int* __restrict__ src,
                      const int* __restrict__ dst,
                      float* __restrict__ out, int A) {
    int i = blockIdx.x * blockDim.x + threadIdx.x;
    if (i >= A) return;
    int s = src[i];
    int d = dst[i];
    float sx = vec[3 * s + 0], sy = vec[3 * s + 1], sz = vec[3 * s + 2];
    float dx = vec[3 * d + 0], dy = vec[3 * d + 1], dz = vec[3 * d + 2];
    float ns = fmaxf(dist[s], 1e-5f);
    float nd = fmaxf(dist[d], 1e-5f);
    float c  = (sx * dx + sy * dy + sz * dz) / (ns * nd);
    out[i] = acosf(0.95f * c);
}

extern "C" void kernel_launch(void* const* d_in, const int* in_sizes, int n_in,
                              void* d_out, int out_size, void* d_ws, size_t ws_size,
                              hipStream_t stream) {
    const float* dist = (const float*)d_in[0];   // [E]
    const float* vec  = (const float*)d_in[1];   // [E,3]
    const int*   src  = (const int*)d_in[2];     // [A]
    const int*   dst  = (const int*)d_in[3];     // [A]
    float*       out  = (float*)d_out;           // [A]

    const int E = in_sizes[0];
    const int A = in_sizes[2];

    const int block = 256;
    if (ws_size >= (size_t)E * sizeof(uint16_t)) {
        uint16_t* tab = (uint16_t*)d_ws;
        int ethreads = (E + 3) / 4;
        encode_kernel<<<(ethreads + block - 1) / block, block, 0, stream>>>(vec, tab, E);
        int athreads = (A + 1) / 2;
        angle_kernel<<<(athreads + block - 1) / block, block, 0, stream>>>(
            tab, src, dst, out, A);
    } else {
        angle_fallback_kernel<<<(A + block - 1) / block, block, 0, stream>>>(
            vec, dist, src, dst, out, A);
    }
}